// Round 4
// baseline (165.402 us; speedup 1.0000x reference)
//
#include <hip/hip_runtime.h>

// Fixed geometry: input (1,16,16,16) -> NIN=4096; kernel (32,16,3,3), pad1 stride1 -> NOUT=8192
#define O_CH  32
#define C_CH  16
#define HH    16
#define WW    16
#define NPIX  256
#define NIN   4096
#define NOUT  8192
#define NB_WEIGHTS 2048   // blocks 0..2047: weight-matrix stores (launched first)
#define NB_BOUNDS  32     // blocks 2048..2079: bounds + concrete forward

typedef float v4f __attribute__((ext_vector_type(4)));

// out layout (floats): x_out[8192] | lb[8192] | ub[8192] | weights[4096*8192] | bias_vec[8192]

// NOTE: no __shared__ anywhere — a previous version allocated 48.6 KB LDS in
// every block, capping the 2048 store blocks at 3 blocks/CU (12 waves/CU).
// Streaming stores need full occupancy (8 blocks / 32 waves per CU).
__global__ __launch_bounds__(256) void fused_deeppoly_kernel(
    const float* __restrict__ x,
    const float* __restrict__ lb,
    const float* __restrict__ ub,
    const float* __restrict__ wk,
    const float* __restrict__ bias,
    float* __restrict__ out) {
    const int b   = blockIdx.x;
    const int tid = threadIdx.x;

    if (b < NB_WEIGHTS) {
        // ---------------- unrolled weight matrix [NIN rows][NOUT cols] ----------------
        // weights[n=(c,h,w)][col=(o,ph,pw)] = K[o,c,h-ph+1,w-pw+1] if offsets in [0,3)
        // Thread owns one float4-column r for 16 consecutive rows; within those rows
        // c,h are fixed and w==j slides 0..15, so the float4 is a sliding window
        // over (k0,k1,k2): 1 select + 3 moves + 1 nontemporal store per row.
        const int colgroup = b & 7;           // 8 groups of 256 float4 across a row
        const int rowset   = b >> 3;          // 256 row-sets of 16 rows
        const int r   = colgroup * 256 + tid; // float4 index within a row (0..2047)
        const int o   = r >> 6;
        const int p   = r & 63;
        const int ph  = p >> 2;
        const int pw0 = (p & 3) << 2;
        const int c   = rowset >> 4;
        const int h   = rowset & 15;
        const int kh  = h - ph + 1;

        float k0 = 0.f, k1 = 0.f, k2 = 0.f;
        if ((unsigned)kh < 3u) {
            const float* kb = wk + ((o * C_CH + c) * 3 + kh) * 3;
            k0 = kb[0]; k1 = kb[1]; k2 = kb[2];
        }
        auto sel = [&](int kw) -> float {
            return kw == 0 ? k0 : (kw == 1 ? k1 : (kw == 2 ? k2 : 0.f));
        };

        v4f* wout = (v4f*)(out + 3 * NOUT);
        v4f* pptr = wout + (size_t)(rowset * 16) * 2048 + r;

        v4f v;
        v.x = sel(1 - pw0);
        v.y = sel(-pw0);
        v.z = sel(-1 - pw0);
        v.w = sel(-2 - pw0);
        #pragma unroll
        for (int j = 0; j < 16; ++j) {
            __builtin_nontemporal_store(v, pptr);
            pptr += 2048;
            v.w = v.z; v.z = v.y; v.y = v.x;
            v.x = sel(j + 2 - pw0);
        }
    } else {
        // ---------------- bounds + concrete forward + bias_vec ----------------
        // Block owns output channel o (256 spatial outputs, one per thread).
        // Inputs (3 x 16 KB) + per-o kernel slice (576 B) are L1/L2-resident;
        // these 32 blocks' load latency hides under the store flood.
        const int o  = b - NB_WEIGHTS;
        const int ph = tid >> 4, pw = tid & 15;
        const float* kb_base = wk + o * C_CH * 9;
        float xa = 0.f, la = 0.f, ua = 0.f;
        #pragma unroll
        for (int c = 0; c < C_CH; ++c) {
            #pragma unroll
            for (int kh = 0; kh < 3; ++kh) {
                int h = ph + kh - 1;
                if ((unsigned)h >= (unsigned)HH) continue;
                #pragma unroll
                for (int kw = 0; kw < 3; ++kw) {
                    int w = pw + kw - 1;
                    if ((unsigned)w >= (unsigned)WW) continue;
                    float k   = kb_base[c * 9 + kh * 3 + kw];
                    int   idx = c * NPIX + h * WW + w;
                    xa = fmaf(k, x[idx], xa);
                    float lv = lb[idx], uv = ub[idx];
                    la = fmaf(k, (k < 0.f) ? uv : lv, la);
                    ua = fmaf(k, (k < 0.f) ? lv : uv, ua);
                }
            }
        }
        const int   t  = o * 256 + tid;
        const float bv = bias[o];
        out[t]            = xa + bv;         // x_out   (bias once)
        out[NOUT + t]     = la + 3.f * bv;   // lb_new  (bias 3x, per reference)
        out[2 * NOUT + t] = ua + 3.f * bv;   // ub_new
        out[(size_t)3 * NOUT + (size_t)NIN * NOUT + t] = bv;  // bias_vec
    }
}

extern "C" void kernel_launch(void* const* d_in, const int* in_sizes, int n_in,
                              void* d_out, int out_size, void* d_ws, size_t ws_size,
                              hipStream_t stream) {
    const float* x    = (const float*)d_in[0];
    const float* lbp  = (const float*)d_in[1];
    const float* ubp  = (const float*)d_in[2];
    // d_in[3] = input_shape (int32), geometry compile-time fixed
    const float* wk   = (const float*)d_in[4];
    const float* bias = (const float*)d_in[5];

    fused_deeppoly_kernel<<<NB_WEIGHTS + NB_BOUNDS, 256, 0, stream>>>(
        x, lbp, ubp, wk, bias, (float*)d_out);
}

// Round 6
// 163.467 us; speedup vs baseline: 1.0118x; 1.0118x over previous
//
#include <hip/hip_runtime.h>

// Fixed geometry: input (1,16,16,16) -> NIN=4096; kernel (32,16,3,3), pad1 stride1 -> NOUT=8192
#define O_CH  32
#define C_CH  16
#define HH    16
#define WW    16
#define NPIX  256
#define NIN   4096
#define NOUT  8192
#define NB_WEIGHTS 2048   // blocks 0..2047: weight-matrix stores, 64 KiB linear each
#define NB_BOUNDS  32     // blocks 2048..2079: bounds + concrete forward

typedef float v4f __attribute__((ext_vector_type(4)));

// out layout (floats): x_out[8192] | lb[8192] | ub[8192] | weights[4096*8192] | bias_vec[8192]
//
// weights[n=(c,h,w)][col=(o,ph,pw)] = K[o,c,h-ph+1,w-pw+1] when offsets in [0,3), else 0.
//
// Store path is deliberately fillBuffer-shaped (plain stores, linear per block):
// block b owns float4 span [b*4096, (b+1)*4096) = rows 2b,2b+1 (64 KiB). Thread t,
// iter i stores float4 (i*256 + t) within the block -> each wave writes 1 KiB
// contiguous, block advances 4 KiB per iteration, fully linear. For this ownership,
// ph=(t&63)>>2, pw0=(t&3)<<2 and kw0=w-pw0+1 are per-thread constants; only
// o = jj*4 + (t>>6) varies -> 3 L1 loads + 4 selects per 16 B store.
__global__ __launch_bounds__(256) void fused_deeppoly_kernel(
    const float* __restrict__ x,
    const float* __restrict__ lb,
    const float* __restrict__ ub,
    const float* __restrict__ wk,
    const float* __restrict__ bias,
    float* __restrict__ out) {
    const int b   = blockIdx.x;
    const int tid = threadIdx.x;

    if (b < NB_WEIGHTS) {
        const int n0   = 2 * b;          // first of the block's two rows
        const int c    = n0 >> 8;
        const int h    = (n0 >> 4) & 15;
        const int w0   = n0 & 15;        // even; second row is w0+1 (no carry)
        const int ph   = (tid & 63) >> 2;
        const int pw0  = (tid & 3) << 2;
        const int osub = tid >> 6;       // 0..3
        const int kh   = h - ph + 1;
        const bool kvalid = (unsigned)kh < 3u;
        const int  khc = kvalid ? kh : 0;        // safe clamp for addressing

        v4f* p = (v4f*)(out + 3 * NOUT) + (size_t)b * 4096 + tid;

        #pragma unroll
        for (int half = 0; half < 2; ++half) {   // row n0, then n0+1
            const int w   = w0 + half;
            const int kw0 = w - pw0 + 1;         // kw of component m is kw0-m
            #pragma unroll
            for (int jj = 0; jj < 8; ++jj) {
                const int o = jj * 4 + osub;
                const float* kb = wk + ((o * C_CH + c) * 3 + khc) * 3;
                float k0 = kb[0], k1 = kb[1], k2 = kb[2];
                if (!kvalid) { k0 = 0.f; k1 = 0.f; k2 = 0.f; }
                auto sel = [&](int kw) -> float {
                    return kw == 0 ? k0 : (kw == 1 ? k1 : (kw == 2 ? k2 : 0.f));
                };
                v4f v;
                v.x = sel(kw0);
                v.y = sel(kw0 - 1);
                v.z = sel(kw0 - 2);
                v.w = sel(kw0 - 3);
                *p = v;                          // plain store (L2 writeback)
                p += 256;                        // +4 KiB, linear within block
            }
        }
    } else {
        // ---------------- bounds + concrete forward + bias_vec ----------------
        // Block owns output channel o (256 spatial outputs, one per thread).
        // Inputs (3 x 16 KB) + kernel slice are L1/L2-resident; latency hides
        // under the store flood.
        const int o  = b - NB_WEIGHTS;
        const int ph = tid >> 4, pw = tid & 15;
        const float* kb_base = wk + o * C_CH * 9;
        float xa = 0.f, la = 0.f, ua = 0.f;
        #pragma unroll
        for (int c = 0; c < C_CH; ++c) {
            #pragma unroll
            for (int kh = 0; kh < 3; ++kh) {
                int h = ph + kh - 1;
                if ((unsigned)h >= (unsigned)HH) continue;
                #pragma unroll
                for (int kw = 0; kw < 3; ++kw) {
                    int w = pw + kw - 1;
                    if ((unsigned)w >= (unsigned)WW) continue;
                    float k   = kb_base[c * 9 + kh * 3 + kw];
                    int   idx = c * NPIX + h * WW + w;
                    xa = fmaf(k, x[idx], xa);
                    float lv = lb[idx], uv = ub[idx];
                    la = fmaf(k, (k < 0.f) ? uv : lv, la);
                    ua = fmaf(k, (k < 0.f) ? lv : uv, ua);
                }
            }
        }
        const int   t  = o * 256 + tid;
        const float bv = bias[o];
        out[t]            = xa + bv;         // x_out   (bias once)
        out[NOUT + t]     = la + 3.f * bv;   // lb_new  (bias 3x, per reference)
        out[2 * NOUT + t] = ua + 3.f * bv;   // ub_new
        out[(size_t)3 * NOUT + (size_t)NIN * NOUT + t] = bv;  // bias_vec
    }
}

extern "C" void kernel_launch(void* const* d_in, const int* in_sizes, int n_in,
                              void* d_out, int out_size, void* d_ws, size_t ws_size,
                              hipStream_t stream) {
    const float* x    = (const float*)d_in[0];
    const float* lbp  = (const float*)d_in[1];
    const float* ubp  = (const float*)d_in[2];
    // d_in[3] = input_shape (int32), geometry compile-time fixed
    const float* wk   = (const float*)d_in[4];
    const float* bias = (const float*)d_in[5];

    fused_deeppoly_kernel<<<NB_WEIGHTS + NB_BOUNDS, 256, 0, stream>>>(
        x, lbp, ubp, wk, bias, (float*)d_out);
}

// Round 7
// 159.786 us; speedup vs baseline: 1.0351x; 1.0230x over previous
//
#include <hip/hip_runtime.h>

// Fixed geometry: input (1,16,16,16) -> NIN=4096; kernel (32,16,3,3), pad1 stride1 -> NOUT=8192
#define O_CH  32
#define C_CH  16
#define HH    16
#define WW    16
#define NPIX  256
#define NIN   4096
#define NOUT  8192
#define NB_BOUNDS  32     // blocks 0..31: bounds + concrete forward + bias_vec
#define NB_WEIGHTS 2048   // blocks 32..2079: weight matrix, global linear sweep

typedef float v4f __attribute__((ext_vector_type(4)));

// out layout (floats): x_out[8192] | lb[8192] | ub[8192] | weights[4096*8192] | bias_vec[8192]
//
// weights[n=(c,h,w)][col=(o,ph,pw)] = K[o,c,h-ph+1,w-pw+1] when offsets in [0,3), else 0.
//
// Store pattern = fillBufferAligned's: global linear sweep. Thread (b,t) stores
// float4 index g = iter*524288 + (b-32)*256 + t; the whole grid advances through
// the 128 MiB buffer in 8 MiB contiguous steps, so concurrent writes cover a
// contiguous multi-MB window (all HBM channels / L2 slices active). The previous
// per-block-64KiB layout put all concurrent writes at the SAME low-16-bit offset
// (channel camping). For this mapping the per-thread decomposition is:
//   column r = (bw&7)*256 + t   -> o, ph, pw0   (loop-invariant)
//   row    n = iter*256 + (bw>>3) -> c = iter, h = nb>>4, w = nb&15 (h,w invariant)
// so the inner loop is: 3 L1 loads (kb += 9), 4 selects w/ invariant conditions,
// 1 plain float4 store, ptr += 8 MiB.
__global__ __launch_bounds__(256) void fused_deeppoly_kernel(
    const float* __restrict__ x,
    const float* __restrict__ lb,
    const float* __restrict__ ub,
    const float* __restrict__ wk,
    const float* __restrict__ bias,
    float* __restrict__ out) {
    const int b   = blockIdx.x;
    const int tid = threadIdx.x;

    if (b >= NB_BOUNDS) {
        // ---------------- unrolled weight matrix [NIN rows][NOUT cols] ----------------
        const int bw  = b - NB_BOUNDS;
        const int nb  = bw >> 3;              // row base: n = iter*256 + nb
        const int r   = (bw & 7) * 256 + tid; // float4 column index (0..2047)
        const int o   = r >> 6;
        const int p   = r & 63;
        const int ph  = p >> 2;
        const int pw0 = (p & 3) << 2;
        const int h   = nb >> 4;
        const int w   = nb & 15;
        const int kh  = h - ph + 1;
        const bool kvalid = (unsigned)kh < 3u;
        const int  khc = kvalid ? kh : 0;     // clamped for safe addressing
        const int  kw0 = w - pw0 + 1;         // kw of component m is kw0-m

        // loop-invariant component selectors (compiler hoists the compares)
        const bool vx0 = kvalid && kw0 == 0, vx1 = kvalid && kw0 == 1, vx2 = kvalid && kw0 == 2;
        const bool vy0 = kvalid && kw0 == 1, vy1 = kvalid && kw0 == 2, vy2 = kvalid && kw0 == 3;
        const bool vz0 = kvalid && kw0 == 2, vz1 = kvalid && kw0 == 3, vz2 = kvalid && kw0 == 4;
        const bool vw0 = kvalid && kw0 == 3, vw1 = kvalid && kw0 == 4, vw2 = kvalid && kw0 == 5;

        const float* kb = wk + (o * C_CH * 3 + khc) * 3;  // c = 0 slice
        v4f* p4 = (v4f*)(out + 3 * NOUT) + (size_t)bw * 256 + tid;

        #pragma unroll
        for (int c = 0; c < C_CH; ++c) {      // c == iter
            const float k0 = kb[0], k1 = kb[1], k2 = kb[2];
            v4f v;
            v.x = vx0 ? k0 : (vx1 ? k1 : (vx2 ? k2 : 0.f));
            v.y = vy0 ? k0 : (vy1 ? k1 : (vy2 ? k2 : 0.f));
            v.z = vz0 ? k0 : (vz1 ? k1 : (vz2 ? k2 : 0.f));
            v.w = vw0 ? k0 : (vw1 ? k1 : (vw2 ? k2 : 0.f));
            *p4 = v;                          // plain store, 1 KiB/wave contiguous
            p4 += 524288;                     // +8 MiB: next grid sweep step
            kb += 9;                          // next input channel
        }
    } else {
        // ---------------- bounds + concrete forward + bias_vec ----------------
        // Block owns output channel o (256 spatial outputs, one per thread).
        // Inputs (3 x 16 KB) + kernel slice are L1/L2-resident; latency hides
        // under the store flood.
        const int o  = b;
        const int ph = tid >> 4, pw = tid & 15;
        const float* kb_base = wk + o * C_CH * 9;
        float xa = 0.f, la = 0.f, ua = 0.f;
        #pragma unroll
        for (int c = 0; c < C_CH; ++c) {
            #pragma unroll
            for (int kh = 0; kh < 3; ++kh) {
                int h = ph + kh - 1;
                if ((unsigned)h >= (unsigned)HH) continue;
                #pragma unroll
                for (int kw = 0; kw < 3; ++kw) {
                    int w = pw + kw - 1;
                    if ((unsigned)w >= (unsigned)WW) continue;
                    float k   = kb_base[c * 9 + kh * 3 + kw];
                    int   idx = c * NPIX + h * WW + w;
                    xa = fmaf(k, x[idx], xa);
                    float lv = lb[idx], uv = ub[idx];
                    la = fmaf(k, (k < 0.f) ? uv : lv, la);
                    ua = fmaf(k, (k < 0.f) ? lv : uv, ua);
                }
            }
        }
        const int   t  = o * 256 + tid;
        const float bv = bias[o];
        out[t]            = xa + bv;         // x_out   (bias once)
        out[NOUT + t]     = la + 3.f * bv;   // lb_new  (bias 3x, per reference)
        out[2 * NOUT + t] = ua + 3.f * bv;   // ub_new
        out[(size_t)3 * NOUT + (size_t)NIN * NOUT + t] = bv;  // bias_vec
    }
}

extern "C" void kernel_launch(void* const* d_in, const int* in_sizes, int n_in,
                              void* d_out, int out_size, void* d_ws, size_t ws_size,
                              hipStream_t stream) {
    const float* x    = (const float*)d_in[0];
    const float* lbp  = (const float*)d_in[1];
    const float* ubp  = (const float*)d_in[2];
    // d_in[3] = input_shape (int32), geometry compile-time fixed
    const float* wk   = (const float*)d_in[4];
    const float* bias = (const float*)d_in[5];

    fused_deeppoly_kernel<<<NB_BOUNDS + NB_WEIGHTS, 256, 0, stream>>>(
        x, lbp, ubp, wk, bias, (float*)d_out);
}